// Round 1
// baseline (3953.138 us; speedup 1.0000x reference)
//
#include <hip/hip_runtime.h>
#include <stdint.h>

typedef unsigned short u16;
typedef short short8 __attribute__((ext_vector_type(8)));
typedef float floatx4 __attribute__((ext_vector_type(4)));

#define D_FEAT 256

__device__ __forceinline__ u16 f2bf(float x){
  unsigned u = __float_as_uint(x);
  u += 0x7FFFu + ((u >> 16) & 1u);   // round-to-nearest-even
  return (u16)(u >> 16);
}

__device__ __forceinline__ short8 pack8(float4 a, float4 b, float sc){
  short8 v;
  v[0]=(short)f2bf(a.x*sc); v[1]=(short)f2bf(a.y*sc); v[2]=(short)f2bf(a.z*sc); v[3]=(short)f2bf(a.w*sc);
  v[4]=(short)f2bf(b.x*sc); v[5]=(short)f2bf(b.y*sc); v[6]=(short)f2bf(b.z*sc); v[7]=(short)f2bf(b.w*sc);
  return v;
}

// wt[n*K + k] = bf16(w[k*N + n])  -- transpose so B-fragments are contiguous in K
__global__ void conv_t_kernel(const float* __restrict__ w, u16* __restrict__ wt, int K, int N){
  int idx = blockIdx.x * 256 + threadIdx.x;
  if (idx >= K * N) return;
  int k = idx / N, n = idx - k * N;
  wt[(size_t)n * K + k] = f2bf(w[idx]);
}

// one wave per edge (grid-stride): gather src row (float4/lane), atomic-scatter into sum[dst]
__global__ void scatter_kernel(const float* __restrict__ feat, const int* __restrict__ sidx,
                               const int* __restrict__ didx, int E,
                               float* __restrict__ sum, float* __restrict__ deg){
  int lane = threadIdx.x & 63;
  int wid = blockIdx.x * (blockDim.x >> 6) + (threadIdx.x >> 6);
  int nw = gridDim.x * (blockDim.x >> 6);
  for (int e = wid; e < E; e += nw){
    int s = sidx[e], d = didx[e];
    float4 v = ((const float4*)(feat + (size_t)s * D_FEAT))[lane];
    float* dp = sum + (size_t)d * D_FEAT + lane * 4;
    atomicAdd(dp + 0, v.x);
    atomicAdd(dp + 1, v.y);
    atomicAdd(dp + 2, v.z);
    atomicAdd(dp + 3, v.w);
    if (lane == 0) atomicAdd(deg + d, 1.0f);
  }
}

// GEMM1: out_bf16[M,256] = relu( concat(h[M,256], sum[M,256]/max(deg,1)) @ W1 + b1 ), K=512
// Bt is [256][512] bf16 (N-major). 128x128 tile, 4 waves, 16x16x32 MFMA.
__global__ __launch_bounds__(256, 2) void gemm1_kernel(
    const float* __restrict__ h, const float* __restrict__ s, const float* __restrict__ deg,
    const u16* __restrict__ Bt, const float* __restrict__ bias,
    u16* __restrict__ out, int M)
{
  const int K = 512;
  __shared__ short8 As8[128 * 5];   // 128 rows x 40 bf16 (pad 32->40: 2-way-conflict-free, 16B aligned)
  __shared__ short8 Bs8[128 * 5];
  int tid = threadIdx.x;
  int wave = tid >> 6, lane = tid & 63;
  int half = lane >> 4, l16 = lane & 15;
  int wr = (wave >> 1) * 64, wc = (wave & 1) * 64;
  int row0 = blockIdx.x * 128, col0 = blockIdx.y * 128;

  floatx4 acc[4][4];
  floatx4 zero4 = {0.f, 0.f, 0.f, 0.f};
#pragma unroll
  for (int i = 0; i < 4; i++)
#pragma unroll
    for (int j = 0; j < 4; j++) acc[i][j] = zero4;

  for (int k0 = 0; k0 < K; k0 += 32){
#pragma unroll
    for (int cc = 0; cc < 2; cc++){
      int c = tid + cc * 256;
      int r = c >> 2, u = c & 3;
      int kk = k0 + u * 8;
      int rg = row0 + r;
      short8 v = {0,0,0,0,0,0,0,0};
      if (rg < M){
        float sc = 1.0f;
        const float* src;
        if (kk < 256){ src = h + (size_t)rg * 256 + kk; }
        else { src = s + (size_t)rg * 256 + (kk - 256); sc = 1.0f / fmaxf(deg[rg], 1.0f); }
        float4 f0 = ((const float4*)src)[0];
        float4 f1 = ((const float4*)src)[1];
        v = pack8(f0, f1, sc);
      }
      As8[r * 5 + u] = v;
      Bs8[r * 5 + u] = *(const short8*)(Bt + (size_t)(col0 + r) * K + kk);
    }
    __syncthreads();
    short8 af[4], bfr[4];
#pragma unroll
    for (int t = 0; t < 4; t++){
      af[t]  = As8[(wr + t * 16 + l16) * 5 + half];
      bfr[t] = Bs8[(wc + t * 16 + l16) * 5 + half];
    }
#pragma unroll
    for (int i = 0; i < 4; i++)
#pragma unroll
      for (int j = 0; j < 4; j++)
        acc[i][j] = __builtin_amdgcn_mfma_f32_16x16x32_bf16(af[i], bfr[j], acc[i][j], 0, 0, 0);
    __syncthreads();
  }

#pragma unroll
  for (int i = 0; i < 4; i++){
    int rbase = row0 + wr + i * 16 + half * 4;
#pragma unroll
    for (int j = 0; j < 4; j++){
      int cg = col0 + wc + j * 16 + l16;
      float bv = bias[cg];
#pragma unroll
      for (int r = 0; r < 4; r++){
        int rg = rbase + r;
        if (rg < M){
          float vv = fmaxf(acc[i][j][r] + bv, 0.0f);
          out[(size_t)rg * 256 + cg] = f2bf(vv);
        }
      }
    }
  }
}

// GEMM2: out_f32[M,256] = A_bf16[M,256] @ W2 + b2 + resid, K=256
__global__ __launch_bounds__(256, 2) void gemm2_kernel(
    const u16* __restrict__ A, const u16* __restrict__ Bt, const float* __restrict__ bias,
    const float* __restrict__ resid, float* __restrict__ out, int M)
{
  const int K = 256;
  __shared__ short8 As8[128 * 5];
  __shared__ short8 Bs8[128 * 5];
  int tid = threadIdx.x;
  int wave = tid >> 6, lane = tid & 63;
  int half = lane >> 4, l16 = lane & 15;
  int wr = (wave >> 1) * 64, wc = (wave & 1) * 64;
  int row0 = blockIdx.x * 128, col0 = blockIdx.y * 128;

  floatx4 acc[4][4];
  floatx4 zero4 = {0.f, 0.f, 0.f, 0.f};
#pragma unroll
  for (int i = 0; i < 4; i++)
#pragma unroll
    for (int j = 0; j < 4; j++) acc[i][j] = zero4;

  for (int k0 = 0; k0 < K; k0 += 32){
#pragma unroll
    for (int cc = 0; cc < 2; cc++){
      int c = tid + cc * 256;
      int r = c >> 2, u = c & 3;
      int kk = k0 + u * 8;
      int rg = row0 + r;
      short8 v = {0,0,0,0,0,0,0,0};
      if (rg < M) v = *(const short8*)(A + (size_t)rg * K + kk);
      As8[r * 5 + u] = v;
      Bs8[r * 5 + u] = *(const short8*)(Bt + (size_t)(col0 + r) * K + kk);
    }
    __syncthreads();
    short8 af[4], bfr[4];
#pragma unroll
    for (int t = 0; t < 4; t++){
      af[t]  = As8[(wr + t * 16 + l16) * 5 + half];
      bfr[t] = Bs8[(wc + t * 16 + l16) * 5 + half];
    }
#pragma unroll
    for (int i = 0; i < 4; i++)
#pragma unroll
      for (int j = 0; j < 4; j++)
        acc[i][j] = __builtin_amdgcn_mfma_f32_16x16x32_bf16(af[i], bfr[j], acc[i][j], 0, 0, 0);
    __syncthreads();
  }

#pragma unroll
  for (int i = 0; i < 4; i++){
    int rbase = row0 + wr + i * 16 + half * 4;
#pragma unroll
    for (int j = 0; j < 4; j++){
      int cg = col0 + wc + j * 16 + l16;
      float bv = bias[cg];
#pragma unroll
      for (int r = 0; r < 4; r++){
        int rg = rbase + r;
        if (rg < M){
          float vv = acc[i][j][r] + bv + resid[(size_t)rg * 256 + cg];
          out[(size_t)rg * 256 + cg] = vv;
        }
      }
    }
  }
}

// LayerNorm over 256 cols, one wave per row (4 rows per 256-thread block)
__global__ void ln_kernel(const float* __restrict__ x, const float* __restrict__ g,
                          const float* __restrict__ b, float* __restrict__ y, int M){
  int row = blockIdx.x * 4 + (threadIdx.x >> 6);
  int lane = threadIdx.x & 63;
  if (row >= M) return;
  float4 v = ((const float4*)(x + (size_t)row * 256))[lane];
  float s1 = v.x + v.y + v.z + v.w;
  float s2 = v.x*v.x + v.y*v.y + v.z*v.z + v.w*v.w;
#pragma unroll
  for (int m = 1; m < 64; m <<= 1){
    s1 += __shfl_xor(s1, m, 64);
    s2 += __shfl_xor(s2, m, 64);
  }
  float mean = s1 * (1.0f / 256.0f);
  float var = s2 * (1.0f / 256.0f) - mean * mean;
  float rs = rsqrtf(var + 1e-5f);
  float4 gv = ((const float4*)g)[lane];
  float4 bv = ((const float4*)b)[lane];
  float4 o;
  o.x = (v.x - mean) * rs * gv.x + bv.x;
  o.y = (v.y - mean) * rs * gv.y + bv.y;
  o.z = (v.z - mean) * rs * gv.z + bv.z;
  o.w = (v.w - mean) * rs * gv.w + bv.w;
  ((float4*)(y + (size_t)row * 256))[lane] = o;
}

extern "C" void kernel_launch(void* const* d_in, const int* in_sizes, int n_in,
                              void* d_out, int out_size, void* d_ws, size_t ws_size,
                              hipStream_t stream){
  const float* cell_h = (const float*)d_in[0];
  const float* net_h  = (const float*)d_in[1];
  const int* e_c2n = (const int*)d_in[2];
  const int* e_n2c = (const int*)d_in[3];
  const int* e_c2c = (const int*)d_in[4];
  const float* w1p[3] = {(const float*)d_in[5], (const float*)d_in[9],  (const float*)d_in[13]};
  const float* b1p[3] = {(const float*)d_in[6], (const float*)d_in[10], (const float*)d_in[14]};
  const float* w2p[3] = {(const float*)d_in[7], (const float*)d_in[11], (const float*)d_in[15]};
  const float* b2p[3] = {(const float*)d_in[8], (const float*)d_in[12], (const float*)d_in[16]};
  const float* net_g  = (const float*)d_in[17];
  const float* net_b  = (const float*)d_in[18];
  const float* cell_g = (const float*)d_in[19];
  const float* cell_b = (const float*)d_in[20];

  int n_cell = in_sizes[0] / 256;
  int n_net  = in_sizes[1] / 256;
  int E = in_sizes[2] / 2;

  float* cell_out = (float*)d_out;
  float* net_out  = (float*)d_out + (size_t)n_cell * 256;

  // workspace layout
  char* p = (char*)d_ws;
  u16* w1t[3]; u16* w2t[3];
  for (int i = 0; i < 3; i++){
    w1t[i] = (u16*)p; p += (size_t)512 * 256 * 2;
    w2t[i] = (u16*)p; p += (size_t)256 * 256 * 2;
  }
  u16* Hbuf   = (u16*)p;  p += (size_t)n_cell * 256 * 2;
  float* Sbuf = (float*)p; p += (size_t)n_cell * 256 * 4;
  float* degb = (float*)p; p += (size_t)n_cell * 4;

  // convert + transpose weights to bf16 [N][K]
  for (int i = 0; i < 3; i++){
    conv_t_kernel<<<(512 * 256 + 255) / 256, 256, 0, stream>>>(w1p[i], w1t[i], 512, 256);
    conv_t_kernel<<<(256 * 256 + 255) / 256, 256, 0, stream>>>(w2p[i], w2t[i], 256, 256);
  }

  dim3 blk(256);

  // ---- stage 1: cells -> nets ----
  hipMemsetAsync(Sbuf, 0, (size_t)n_net * 256 * 4, stream);
  hipMemsetAsync(degb, 0, (size_t)n_net * 4, stream);
  scatter_kernel<<<2048, 256, 0, stream>>>(cell_h, e_c2n, e_c2n + E, E, Sbuf, degb);
  {
    dim3 g((n_net + 127) / 128, 2);
    gemm1_kernel<<<g, blk, 0, stream>>>(net_h, Sbuf, degb, w1t[0], b1p[0], Hbuf, n_net);
    gemm2_kernel<<<g, blk, 0, stream>>>(Hbuf, w2t[0], b2p[0], net_h, Sbuf, n_net);
  }
  ln_kernel<<<(n_net + 3) / 4, 256, 0, stream>>>(Sbuf, net_g, net_b, net_out, n_net);

  // ---- stage 2: nets -> cells (no LN) ----
  hipMemsetAsync(Sbuf, 0, (size_t)n_cell * 256 * 4, stream);
  hipMemsetAsync(degb, 0, (size_t)n_cell * 4, stream);
  scatter_kernel<<<2048, 256, 0, stream>>>(net_out, e_n2c, e_n2c + E, E, Sbuf, degb);
  {
    dim3 g((n_cell + 127) / 128, 2);
    gemm1_kernel<<<g, blk, 0, stream>>>(cell_h, Sbuf, degb, w1t[1], b1p[1], Hbuf, n_cell);
    gemm2_kernel<<<g, blk, 0, stream>>>(Hbuf, w2t[1], b2p[1], cell_h, cell_out, n_cell);
  }

  // ---- stage 3: cells -> cells, then LN ----
  hipMemsetAsync(Sbuf, 0, (size_t)n_cell * 256 * 4, stream);
  hipMemsetAsync(degb, 0, (size_t)n_cell * 4, stream);
  scatter_kernel<<<2048, 256, 0, stream>>>(cell_out, e_c2c, e_c2c + E, E, Sbuf, degb);
  {
    dim3 g((n_cell + 127) / 128, 2);
    gemm1_kernel<<<g, blk, 0, stream>>>(cell_out, Sbuf, degb, w1t[2], b1p[2], Hbuf, n_cell);
    gemm2_kernel<<<g, blk, 0, stream>>>(Hbuf, w2t[2], b2p[2], cell_out, Sbuf, n_cell);
  }
  ln_kernel<<<(n_cell + 3) / 4, 256, 0, stream>>>(Sbuf, cell_g, cell_b, cell_out, n_cell);
}

// Round 2
// 1153.328 us; speedup vs baseline: 3.4276x; 3.4276x over previous
//
#include <hip/hip_runtime.h>
#include <stdint.h>

typedef unsigned short u16;
typedef short short8 __attribute__((ext_vector_type(8)));
typedef float floatx4 __attribute__((ext_vector_type(4)));

#define D_FEAT 256

__device__ __forceinline__ u16 f2bf(float x){
  unsigned u = __float_as_uint(x);
  u += 0x7FFFu + ((u >> 16) & 1u);   // round-to-nearest-even
  return (u16)(u >> 16);
}

__device__ __forceinline__ short8 pack8(float4 a, float4 b){
  short8 v;
  v[0]=(short)f2bf(a.x); v[1]=(short)f2bf(a.y); v[2]=(short)f2bf(a.z); v[3]=(short)f2bf(a.w);
  v[4]=(short)f2bf(b.x); v[5]=(short)f2bf(b.y); v[6]=(short)f2bf(b.z); v[7]=(short)f2bf(b.w);
  return v;
}

// wt[n*K + k] = bf16(w[k*N + n])  -- transpose so B-fragments are contiguous in K
__global__ void conv_t_kernel(const float* __restrict__ w, u16* __restrict__ wt, int K, int N){
  int idx = blockIdx.x * 256 + threadIdx.x;
  if (idx >= K * N) return;
  int k = idx / N, n = idx - k * N;
  wt[(size_t)n * K + k] = f2bf(w[idx]);
}

// ---------------- CSR build ----------------
__global__ void hist_kernel(const int* __restrict__ didx, int E, int* __restrict__ cnt){
  int e = blockIdx.x * 256 + threadIdx.x;
  if (e < E) atomicAdd(&cnt[didx[e]], 1);
}

// exclusive scan, 256 elems per block
__global__ void scan_block_kernel(const int* __restrict__ cnt, int* __restrict__ excl,
                                  int* __restrict__ bsums, int N){
  __shared__ int tmp[256];
  int t = threadIdx.x;
  int i = blockIdx.x * 256 + t;
  int v = (i < N) ? cnt[i] : 0;
  tmp[t] = v; __syncthreads();
#pragma unroll
  for (int o = 1; o < 256; o <<= 1){
    int x = (t >= o) ? tmp[t - o] : 0;
    __syncthreads();
    tmp[t] += x;
    __syncthreads();
  }
  if (i < N) excl[i] = tmp[t] - v;
  if (t == 255) bsums[blockIdx.x] = tmp[255];
}

__global__ void scan_bsums_kernel(int* __restrict__ bsums, int nb){
  if (blockIdx.x == 0 && threadIdx.x == 0){
    int acc = 0;
    for (int i = 0; i < nb; i++){ int v = bsums[i]; bsums[i] = acc; acc += v; }
  }
}

__global__ void scan_add_kernel(int* __restrict__ excl, const int* __restrict__ bsums, int N){
  int i = blockIdx.x * 256 + threadIdx.x;
  if (i < N) excl[i] += bsums[blockIdx.x];
}

__global__ void fill_csr_kernel(const int* __restrict__ sidx, const int* __restrict__ didx, int E,
                                const int* __restrict__ row_start, int* __restrict__ fillc,
                                int* __restrict__ esrc){
  int e = blockIdx.x * 256 + threadIdx.x;
  if (e >= E) return;
  int d = didx[e];
  int pos = atomicAdd(&fillc[d], 1);
  esrc[row_start[d] + pos] = sidx[e];
}

// one wave per dst row: gather src rows, accumulate fp32, write mean
__global__ void agg_mean_kernel(const float* __restrict__ feat, const int* __restrict__ row_start,
                                const int* __restrict__ cnt, const int* __restrict__ esrc,
                                float* __restrict__ mean, int M){
  int row = blockIdx.x * 4 + (threadIdx.x >> 6);
  int lane = threadIdx.x & 63;
  if (row >= M) return;
  int beg = row_start[row], n = cnt[row];
  float4 a0 = {0.f,0.f,0.f,0.f}, a1 = {0.f,0.f,0.f,0.f};
  int j = 0;
  for (; j + 1 < n; j += 2){
    int s0 = esrc[beg + j], s1 = esrc[beg + j + 1];
    float4 v0 = ((const float4*)(feat + (size_t)s0 * D_FEAT))[lane];
    float4 v1 = ((const float4*)(feat + (size_t)s1 * D_FEAT))[lane];
    a0.x += v0.x; a0.y += v0.y; a0.z += v0.z; a0.w += v0.w;
    a1.x += v1.x; a1.y += v1.y; a1.z += v1.z; a1.w += v1.w;
  }
  if (j < n){
    int s0 = esrc[beg + j];
    float4 v0 = ((const float4*)(feat + (size_t)s0 * D_FEAT))[lane];
    a0.x += v0.x; a0.y += v0.y; a0.z += v0.z; a0.w += v0.w;
  }
  float inv = 1.0f / fmaxf((float)n, 1.0f);
  float4 o;
  o.x = (a0.x + a1.x) * inv; o.y = (a0.y + a1.y) * inv;
  o.z = (a0.z + a1.z) * inv; o.w = (a0.w + a1.w) * inv;
  ((float4*)(mean + (size_t)row * D_FEAT))[lane] = o;
}

// ---------------- GEMMs ----------------
// GEMM1: out_bf16[M,256] = relu( concat(h[M,256], mean[M,256]) @ W1 + b1 ), K=512
__global__ __launch_bounds__(256, 2) void gemm1_kernel(
    const float* __restrict__ h, const float* __restrict__ s,
    const u16* __restrict__ Bt, const float* __restrict__ bias,
    u16* __restrict__ out, int M)
{
  const int K = 512;
  __shared__ short8 As8[128 * 5];   // 128 rows x 40 bf16 (pad 32->40)
  __shared__ short8 Bs8[128 * 5];
  int tid = threadIdx.x;
  int wave = tid >> 6, lane = tid & 63;
  int half = lane >> 4, l16 = lane & 15;
  int wr = (wave >> 1) * 64, wc = (wave & 1) * 64;
  int row0 = blockIdx.x * 128, col0 = blockIdx.y * 128;

  floatx4 acc[4][4];
  floatx4 zero4 = {0.f, 0.f, 0.f, 0.f};
#pragma unroll
  for (int i = 0; i < 4; i++)
#pragma unroll
    for (int j = 0; j < 4; j++) acc[i][j] = zero4;

  for (int k0 = 0; k0 < K; k0 += 32){
#pragma unroll
    for (int cc = 0; cc < 2; cc++){
      int c = tid + cc * 256;
      int r = c >> 2, u = c & 3;
      int kk = k0 + u * 8;
      int rg = row0 + r;
      short8 v = {0,0,0,0,0,0,0,0};
      if (rg < M){
        const float* src = (kk < 256) ? (h + (size_t)rg * 256 + kk)
                                      : (s + (size_t)rg * 256 + (kk - 256));
        float4 f0 = ((const float4*)src)[0];
        float4 f1 = ((const float4*)src)[1];
        v = pack8(f0, f1);
      }
      As8[r * 5 + u] = v;
      Bs8[r * 5 + u] = *(const short8*)(Bt + (size_t)(col0 + r) * K + kk);
    }
    __syncthreads();
    short8 af[4], bfr[4];
#pragma unroll
    for (int t = 0; t < 4; t++){
      af[t]  = As8[(wr + t * 16 + l16) * 5 + half];
      bfr[t] = Bs8[(wc + t * 16 + l16) * 5 + half];
    }
#pragma unroll
    for (int i = 0; i < 4; i++)
#pragma unroll
      for (int j = 0; j < 4; j++)
        acc[i][j] = __builtin_amdgcn_mfma_f32_16x16x32_bf16(af[i], bfr[j], acc[i][j], 0, 0, 0);
    __syncthreads();
  }

#pragma unroll
  for (int i = 0; i < 4; i++){
    int rbase = row0 + wr + i * 16 + half * 4;
#pragma unroll
    for (int j = 0; j < 4; j++){
      int cg = col0 + wc + j * 16 + l16;
      float bv = bias[cg];
#pragma unroll
      for (int r = 0; r < 4; r++){
        int rg = rbase + r;
        if (rg < M){
          float vv = fmaxf(acc[i][j][r] + bv, 0.0f);
          out[(size_t)rg * 256 + cg] = f2bf(vv);
        }
      }
    }
  }
}

// GEMM2: out_f32[M,256] = A_bf16[M,256] @ W2 + b2 + resid, K=256
__global__ __launch_bounds__(256, 2) void gemm2_kernel(
    const u16* __restrict__ A, const u16* __restrict__ Bt, const float* __restrict__ bias,
    const float* __restrict__ resid, float* __restrict__ out, int M)
{
  const int K = 256;
  __shared__ short8 As8[128 * 5];
  __shared__ short8 Bs8[128 * 5];
  int tid = threadIdx.x;
  int wave = tid >> 6, lane = tid & 63;
  int half = lane >> 4, l16 = lane & 15;
  int wr = (wave >> 1) * 64, wc = (wave & 1) * 64;
  int row0 = blockIdx.x * 128, col0 = blockIdx.y * 128;

  floatx4 acc[4][4];
  floatx4 zero4 = {0.f, 0.f, 0.f, 0.f};
#pragma unroll
  for (int i = 0; i < 4; i++)
#pragma unroll
    for (int j = 0; j < 4; j++) acc[i][j] = zero4;

  for (int k0 = 0; k0 < K; k0 += 32){
#pragma unroll
    for (int cc = 0; cc < 2; cc++){
      int c = tid + cc * 256;
      int r = c >> 2, u = c & 3;
      int kk = k0 + u * 8;
      int rg = row0 + r;
      short8 v = {0,0,0,0,0,0,0,0};
      if (rg < M) v = *(const short8*)(A + (size_t)rg * K + kk);
      As8[r * 5 + u] = v;
      Bs8[r * 5 + u] = *(const short8*)(Bt + (size_t)(col0 + r) * K + kk);
    }
    __syncthreads();
    short8 af[4], bfr[4];
#pragma unroll
    for (int t = 0; t < 4; t++){
      af[t]  = As8[(wr + t * 16 + l16) * 5 + half];
      bfr[t] = Bs8[(wc + t * 16 + l16) * 5 + half];
    }
#pragma unroll
    for (int i = 0; i < 4; i++)
#pragma unroll
      for (int j = 0; j < 4; j++)
        acc[i][j] = __builtin_amdgcn_mfma_f32_16x16x32_bf16(af[i], bfr[j], acc[i][j], 0, 0, 0);
    __syncthreads();
  }

#pragma unroll
  for (int i = 0; i < 4; i++){
    int rbase = row0 + wr + i * 16 + half * 4;
#pragma unroll
    for (int j = 0; j < 4; j++){
      int cg = col0 + wc + j * 16 + l16;
      float bv = bias[cg];
#pragma unroll
      for (int r = 0; r < 4; r++){
        int rg = rbase + r;
        if (rg < M){
          float vv = acc[i][j][r] + bv + resid[(size_t)rg * 256 + cg];
          out[(size_t)rg * 256 + cg] = vv;
        }
      }
    }
  }
}

// LayerNorm over 256 cols, one wave per row
__global__ void ln_kernel(const float* __restrict__ x, const float* __restrict__ g,
                          const float* __restrict__ b, float* __restrict__ y, int M){
  int row = blockIdx.x * 4 + (threadIdx.x >> 6);
  int lane = threadIdx.x & 63;
  if (row >= M) return;
  float4 v = ((const float4*)(x + (size_t)row * 256))[lane];
  float s1 = v.x + v.y + v.z + v.w;
  float s2 = v.x*v.x + v.y*v.y + v.z*v.z + v.w*v.w;
#pragma unroll
  for (int m = 1; m < 64; m <<= 1){
    s1 += __shfl_xor(s1, m, 64);
    s2 += __shfl_xor(s2, m, 64);
  }
  float mean = s1 * (1.0f / 256.0f);
  float var = s2 * (1.0f / 256.0f) - mean * mean;
  float rs = rsqrtf(var + 1e-5f);
  float4 gv = ((const float4*)g)[lane];
  float4 bv = ((const float4*)b)[lane];
  float4 o;
  o.x = (v.x - mean) * rs * gv.x + bv.x;
  o.y = (v.y - mean) * rs * gv.y + bv.y;
  o.z = (v.z - mean) * rs * gv.z + bv.z;
  o.w = (v.w - mean) * rs * gv.w + bv.w;
  ((float4*)(y + (size_t)row * 256))[lane] = o;
}

// helper: build CSR + aggregate mean for one stage
static void run_agg(const float* feat, const int* edge, int E, int Ndst,
                    int* cnt, int* row_start, int* fillc, int* bsums, int* esrc,
                    float* mean, hipStream_t stream){
  const int* sidx = edge;
  const int* didx = edge + E;
  hipMemsetAsync(cnt, 0, (size_t)Ndst * 4, stream);
  hipMemsetAsync(fillc, 0, (size_t)Ndst * 4, stream);
  int egrid = (E + 255) / 256;
  hist_kernel<<<egrid, 256, 0, stream>>>(didx, E, cnt);
  int nb = (Ndst + 255) / 256;
  scan_block_kernel<<<nb, 256, 0, stream>>>(cnt, row_start, bsums, Ndst);
  scan_bsums_kernel<<<1, 1, 0, stream>>>(bsums, nb);
  scan_add_kernel<<<nb, 256, 0, stream>>>(row_start, bsums, Ndst);
  fill_csr_kernel<<<egrid, 256, 0, stream>>>(sidx, didx, E, row_start, fillc, esrc);
  agg_mean_kernel<<<(Ndst + 3) / 4, 256, 0, stream>>>(feat, row_start, cnt, esrc, mean, Ndst);
}

extern "C" void kernel_launch(void* const* d_in, const int* in_sizes, int n_in,
                              void* d_out, int out_size, void* d_ws, size_t ws_size,
                              hipStream_t stream){
  const float* cell_h = (const float*)d_in[0];
  const float* net_h  = (const float*)d_in[1];
  const int* e_c2n = (const int*)d_in[2];
  const int* e_n2c = (const int*)d_in[3];
  const int* e_c2c = (const int*)d_in[4];
  const float* w1p[3] = {(const float*)d_in[5], (const float*)d_in[9],  (const float*)d_in[13]};
  const float* b1p[3] = {(const float*)d_in[6], (const float*)d_in[10], (const float*)d_in[14]};
  const float* w2p[3] = {(const float*)d_in[7], (const float*)d_in[11], (const float*)d_in[15]};
  const float* b2p[3] = {(const float*)d_in[8], (const float*)d_in[12], (const float*)d_in[16]};
  const float* net_g  = (const float*)d_in[17];
  const float* net_b  = (const float*)d_in[18];
  const float* cell_g = (const float*)d_in[19];
  const float* cell_b = (const float*)d_in[20];

  int n_cell = in_sizes[0] / 256;
  int n_net  = in_sizes[1] / 256;
  int E = in_sizes[2] / 2;

  float* cell_out = (float*)d_out;
  float* net_out  = (float*)d_out + (size_t)n_cell * 256;

  // workspace layout
  char* p = (char*)d_ws;
  u16* w1t[3]; u16* w2t[3];
  for (int i = 0; i < 3; i++){
    w1t[i] = (u16*)p; p += (size_t)512 * 256 * 2;
    w2t[i] = (u16*)p; p += (size_t)256 * 256 * 2;
  }
  u16* Hbuf   = (u16*)p;  p += (size_t)n_cell * 256 * 2;   // bf16 MLP-hidden, also aliases CSR scratch
  float* Mbuf = (float*)p; p += (size_t)n_cell * 256 * 4;  // fp32 mean, then gemm2 output

  // CSR scratch aliased into Hbuf (dead until gemm1 writes it; CSR consumed by then)
  int n_pad = ((n_cell + 63) / 64) * 64;
  int* cnt       = (int*)Hbuf;
  int* row_start = cnt + n_pad;
  int* fillc     = row_start + n_pad;
  int* bsums     = fillc + n_pad;      // up to 1024 block sums
  int* esrc      = bsums + 1024;

  // convert + transpose weights to bf16 [N][K]
  for (int i = 0; i < 3; i++){
    conv_t_kernel<<<(512 * 256 + 255) / 256, 256, 0, stream>>>(w1p[i], w1t[i], 512, 256);
    conv_t_kernel<<<(256 * 256 + 255) / 256, 256, 0, stream>>>(w2p[i], w2t[i], 256, 256);
  }

  dim3 blk(256);

  // ---- stage 1: cells -> nets ----
  run_agg(cell_h, e_c2n, E, n_net, cnt, row_start, fillc, bsums, esrc, Mbuf, stream);
  {
    dim3 g((n_net + 127) / 128, 2);
    gemm1_kernel<<<g, blk, 0, stream>>>(net_h, Mbuf, w1t[0], b1p[0], Hbuf, n_net);
    gemm2_kernel<<<g, blk, 0, stream>>>(Hbuf, w2t[0], b2p[0], net_h, Mbuf, n_net);
  }
  ln_kernel<<<(n_net + 3) / 4, 256, 0, stream>>>(Mbuf, net_g, net_b, net_out, n_net);

  // ---- stage 2: nets -> cells (no LN) ----
  run_agg(net_out, e_n2c, E, n_cell, cnt, row_start, fillc, bsums, esrc, Mbuf, stream);
  {
    dim3 g((n_cell + 127) / 128, 2);
    gemm1_kernel<<<g, blk, 0, stream>>>(cell_h, Mbuf, w1t[1], b1p[1], Hbuf, n_cell);
    gemm2_kernel<<<g, blk, 0, stream>>>(Hbuf, w2t[1], b2p[1], cell_h, cell_out, n_cell);
  }

  // ---- stage 3: cells -> cells, then LN ----
  run_agg(cell_out, e_c2c, E, n_cell, cnt, row_start, fillc, bsums, esrc, Mbuf, stream);
  {
    dim3 g((n_cell + 127) / 128, 2);
    gemm1_kernel<<<g, blk, 0, stream>>>(cell_out, Mbuf, w1t[2], b1p[2], Hbuf, n_cell);
    gemm2_kernel<<<g, blk, 0, stream>>>(Hbuf, w2t[2], b2p[2], cell_out, Mbuf, n_cell);
  }
  ln_kernel<<<(n_cell + 3) / 4, 256, 0, stream>>>(Mbuf, cell_g, cell_b, cell_out, n_cell);
}